// Round 3
// baseline (651.840 us; speedup 1.0000x reference)
//
#include <hip/hip_runtime.h>
#include <hip/hip_bf16.h>
#include <cstdint>
#include <cstddef>

#define DM   256
#define DI   512
#define DTR  16
#define DS   16
#define LSEQ 4096
#define BATCH 2
#define BLROWS (BATCH * LSEQ)   /* 8192 */
#define NCH  64                 /* chunks per sequence */
#define CLEN 64                 /* steps per chunk */

typedef __bf16 bf16x8 __attribute__((ext_vector_type(8)));
typedef float  f32x4  __attribute__((ext_vector_type(4)));
typedef unsigned short u16;
typedef u16 u16x8 __attribute__((ext_vector_type(8)));
typedef u16 u16x4 __attribute__((ext_vector_type(4)));

__device__ __forceinline__ u16 f2bfu(float f) {
    union { float f; unsigned u; } c; c.f = f;
    unsigned u = c.u;
    return (u16)((u + 0x7fffu + ((u >> 16) & 1u)) >> 16);
}
__device__ __forceinline__ float bfu2f(u16 u) {
    union { unsigned u; float f; } c; c.u = ((unsigned)u) << 16; return c.f;
}
__device__ __forceinline__ float siluf(float v) {
    return v * (1.0f / (1.0f + __expf(-v)));
}

/* device-scope grid barrier: co-residency guaranteed (LDS allows 3 blk/CU, grid=2/CU) */
__device__ __forceinline__ void grid_barrier(unsigned* bar, unsigned target) {
    __syncthreads();
    if (threadIdx.x == 0) {
        __hip_atomic_fetch_add(bar, 1u, __ATOMIC_ACQ_REL, __HIP_MEMORY_SCOPE_AGENT);
        while (__hip_atomic_load(bar, __ATOMIC_ACQUIRE, __HIP_MEMORY_SCOPE_AGENT) < target)
            __builtin_amdgcn_s_sleep(1);
    }
    __syncthreads();
}

/* ---------------- weight casts ---------------- */
__global__ __launch_bounds__(256) void cast_f32_bf16_k(
    const float* __restrict__ s, u16* __restrict__ d, int n) {
    int i = blockIdx.x * 256 + threadIdx.x;
    if (i < n) d[i] = f2bfu(s[i]);
}

/* pad x_proj_w [2,48,512] -> [2,64,512] bf16 (rows 48..63 zero) */
__global__ __launch_bounds__(256) void cast_xp_pad_k(
    const float* __restrict__ s, u16* __restrict__ d) {
    int i = blockIdx.x * 256 + threadIdx.x;     /* 2*64*512 = 65536 */
    int k = i & 511, o = (i >> 9) & 63, l = i >> 15;
    float v = (o < 48) ? s[(l * 48 + o) * 512 + k] : 0.0f;
    d[i] = f2bfu(v);
}

/* ---------------- bf16 MFMA GEMM: C[M,N] = A[M,K] * B[N,K]^T, f32/bf16 out ---- */
__global__ __launch_bounds__(256) void gemm_bt_k(
    const __bf16* __restrict__ A, const __bf16* __restrict__ B,
    float* __restrict__ Cf, u16* __restrict__ Cb, int M, int N, int K) {
    int tid  = threadIdx.x;
    int wave = tid >> 6, lane = tid & 63;
    int row  = lane & 15, q = lane >> 4;
    int bm = blockIdx.x * 64, bn = blockIdx.y * 64;
    int wm = bm + (wave & 1) * 32, wn = bn + (wave >> 1) * 32;
    f32x4 acc00 = {0.f,0.f,0.f,0.f}, acc01 = acc00, acc10 = acc00, acc11 = acc00;
    const bf16x8* Av = (const bf16x8*)A;
    const bf16x8* Bv = (const bf16x8*)B;
    int sK = K >> 3;
    for (int k0 = 0; k0 < K; k0 += 32) {
        int kb = (k0 >> 3) + q;
        bf16x8 a0 = Av[(size_t)(wm + row)      * sK + kb];
        bf16x8 a1 = Av[(size_t)(wm + 16 + row) * sK + kb];
        bf16x8 b0 = Bv[(size_t)(wn + row)      * sK + kb];
        bf16x8 b1 = Bv[(size_t)(wn + 16 + row) * sK + kb];
        acc00 = __builtin_amdgcn_mfma_f32_16x16x32_bf16(a0, b0, acc00, 0, 0, 0);
        acc01 = __builtin_amdgcn_mfma_f32_16x16x32_bf16(a0, b1, acc01, 0, 0, 0);
        acc10 = __builtin_amdgcn_mfma_f32_16x16x32_bf16(a1, b0, acc10, 0, 0, 0);
        acc11 = __builtin_amdgcn_mfma_f32_16x16x32_bf16(a1, b1, acc11, 0, 0, 0);
    }
    /* C/D layout: col = lane&15, row = q*4 + r */
    #pragma unroll
    for (int r = 0; r < 4; ++r) {
        size_t r0 = (size_t)(wm + q*4 + r) * N, r1 = (size_t)(wm + 16 + q*4 + r) * N;
        if (Cf) {
            Cf[r0 + wn + row]      = acc00[r];
            Cf[r0 + wn + 16 + row] = acc01[r];
            Cf[r1 + wn + row]      = acc10[r];
            Cf[r1 + wn + 16 + row] = acc11[r];
        }
        if (Cb) {
            Cb[r0 + wn + row]      = f2bfu(acc00[r]);
            Cb[r0 + wn + 16 + row] = f2bfu(acc01[r]);
            Cb[r1 + wn + row]      = f2bfu(acc10[r]);
            Cb[r1 + wn + 16 + row] = f2bfu(acc11[r]);
        }
    }
}

/* ---------------- causal depthwise conv (taps=4) + bias + silu, bf16 in/out --- */
/* also zeroes the grid-barrier counters for the following scan kernel */
__global__ __launch_bounds__(256) void conv_silu_k(
    const u16* __restrict__ xz, const float* __restrict__ cw,
    const float* __restrict__ cb, u16* __restrict__ xcb,
    unsigned* __restrict__ bar) {
    int i = blockIdx.x * 256 + threadIdx.x;   /* BLROWS*DI */
    if (i < 2) bar[i] = 0;
    int d = i & (DI - 1); int bl = i >> 9;
    int l = bl & (LSEQ - 1);
    float acc = cb[d];
    #pragma unroll
    for (int j = 0; j < 4; ++j) {
        int ll = l - 3 + j;
        if (ll >= 0) acc = fmaf(bfu2f(xz[(size_t)(bl - 3 + j) * (2*DI) + d]), cw[d*4 + j], acc);
    }
    xcb[i] = f2bfu(siluf(acc));
}

/* ---------------- fused selective scan: A (chunk scan) | B (stitch) | C -------- */
/* grid (DI/128=4, NCH=64, BATCH=2) = 512 blocks, 256 thr: 2 threads per d (n split 8+8) */
__global__ __launch_bounds__(256) void scan_fused_k(
    const u16* __restrict__ xcb, const float* __restrict__ xdbl,
    const float* __restrict__ dtw, const float* __restrict__ dtb,
    const float* __restrict__ Alog, const float* __restrict__ Dp,
    const u16* __restrict__ xz, u16* __restrict__ Pb, u16* __restrict__ Sb,
    float* __restrict__ H, u16* __restrict__ yout, unsigned* __restrict__ bar) {
    __shared__ u16 dts[CLEN * 128];        /* 16 KB */
    __shared__ u16 xcs[CLEN * 128];        /* 16 KB */
    __shared__ float dt16s[CLEN * 16];     /* 4 KB */
    __shared__ float Bs[CLEN * 16];        /* 4 KB */
    __shared__ float Cs[CLEN * 16];        /* 4 KB */
    int tid = threadIdx.x;
    int dg = blockIdx.x, c = blockIdx.y, b = blockIdx.z;
    int dLocal = tid >> 1, nh = tid & 1;
    int d = dg * 128 + dLocal;
    int bl0 = b * LSEQ + c * CLEN;

    /* stage xc slab: [t][dLocal], wide loads */
    for (int idx = tid; idx < CLEN * 128 / 8; idx += 256) {
        int row = idx >> 4, col = idx & 15;
        ((u16x8*)xcs)[idx] =
            ((const u16x8*)(xcb + (size_t)(bl0 + row) * DI + dg * 128))[col];
    }
    /* stage x_dbl cols 0..47 -> dt16s | Bs | Cs */
    for (int idx = tid; idx < CLEN * 12; idx += 256) {
        int row = idx / 12, g = idx - row * 12;
        f32x4 v = ((const f32x4*)(xdbl + (size_t)(bl0 + row) * 64))[g];
        float* dst = (g < 4) ? &dt16s[row*16 + g*4]
                   : (g < 8) ? &Bs[row*16 + (g-4)*4]
                             : &Cs[row*16 + (g-8)*4];
        *(f32x4*)dst = v;
    }
    /* per-thread constants */
    float dtwr[16];
    {
        const f32x4* w4 = (const f32x4*)(dtw + (size_t)d * 16);
        #pragma unroll
        for (int g = 0; g < 4; ++g) { f32x4 v = w4[g];
            dtwr[g*4] = v[0]; dtwr[g*4+1] = v[1]; dtwr[g*4+2] = v[2]; dtwr[g*4+3] = v[3]; }
    }
    float dtbv = dtb[d];
    float Ac[8];
    {
        const f32x4* a4 = (const f32x4*)(Alog + (size_t)d * 16 + nh * 8);
        f32x4 a0 = a4[0], a1 = a4[1];
        #pragma unroll
        for (int j = 0; j < 4; ++j) { Ac[j] = -__expf(a0[j]); Ac[4+j] = -__expf(a1[j]); }
    }
    __syncthreads();

    /* ---- phase A: local chunk scan ---- */
    float p[8], s[8];
    #pragma unroll
    for (int j = 0; j < 8; ++j) { p[j] = 1.0f; s[j] = 0.0f; }
    for (int t = 0; t < CLEN; ++t) {
        float acc = dtbv;
        #pragma unroll
        for (int r = 0; r < 16; ++r) acc = fmaf(dt16s[t*16 + r], dtwr[r], acc);
        float dt = (acc > 20.0f) ? acc : logf(1.0f + __expf(acc));
        if (nh == 0) dts[t*128 + dLocal] = f2bfu(dt);
        float xv = bfu2f(xcs[t*128 + dLocal]);
        float dx = dt * xv;
        #pragma unroll
        for (int j = 0; j < 8; ++j) {
            float a = __expf(dt * Ac[j]);
            s[j] = fmaf(a, s[j], Bs[t*16 + nh*8 + j] * dx);
            p[j] *= a;
        }
    }
    {
        size_t base = ((size_t)(b*NCH + c) * DI + d) * 16 + nh * 8;
        u16x8 pv, sv;
        #pragma unroll
        for (int j = 0; j < 8; ++j) { pv[j] = f2bfu(p[j]); sv[j] = f2bfu(s[j]); }
        *(u16x8*)(Pb + base) = pv;
        *(u16x8*)(Sb + base) = sv;
    }
    grid_barrier(bar + 0, 512);

    /* ---- phase B: stitch chunk entry states (first 4096 threads) ---- */
    int bid = blockIdx.x + 4 * (blockIdx.y + 64 * blockIdx.z);
    int gid = bid * 256 + tid;
    if (gid < 4096) {
        int bb = gid >> 11, j4 = gid & 2047;
        f32x4 h = {0.f, 0.f, 0.f, 0.f};
        for (int cc = 0; cc < NCH; ++cc) {
            size_t i4 = (size_t)(bb*NCH + cc) * 2048 + j4;
            u16x4 pv = ((const u16x4*)Pb)[i4];
            u16x4 sv = ((const u16x4*)Sb)[i4];
            ((f32x4*)H)[i4] = h;
            #pragma unroll
            for (int j = 0; j < 4; ++j) h[j] = fmaf(bfu2f(pv[j]), h[j], bfu2f(sv[j]));
        }
    }
    grid_barrier(bar + 1, 512);

    /* ---- phase C: replay with correct entry state, emit y*silu(gate) ---- */
    float h[8];
    {
        const f32x4* h4 = (const f32x4*)(H + ((size_t)(b*NCH + c) * DI + d) * 16 + nh * 8);
        f32x4 h0 = h4[0], h1 = h4[1];
        #pragma unroll
        for (int j = 0; j < 4; ++j) { h[j] = h0[j]; h[4+j] = h1[j]; }
    }
    float Dv = Dp[d];
    for (int t = 0; t < CLEN; ++t) {
        float dt = bfu2f(dts[t*128 + dLocal]);
        float xv = bfu2f(xcs[t*128 + dLocal]);
        float dx = dt * xv;
        float y = 0.f;
        #pragma unroll
        for (int j = 0; j < 8; ++j) {
            float a = __expf(dt * Ac[j]);
            h[j] = fmaf(a, h[j], Bs[t*16 + nh*8 + j] * dx);
            y = fmaf(h[j], Cs[t*16 + nh*8 + j], y);
        }
        y += __shfl_xor(y, 1, 64);
        float gv = bfu2f(xz[(size_t)(bl0 + t) * (2*DI) + DI + d]);
        float yv = fmaf(xv, Dv, y) * siluf(gv);
        if (nh == 0) yout[(size_t)(bl0 + t) * DI + d] = f2bfu(yv);
    }
}

/* ================================================================== */
extern "C" void kernel_launch(void* const* d_in, const int* in_sizes, int n_in,
                              void* d_out, int out_size, void* d_ws, size_t ws_size,
                              hipStream_t stream) {
    (void)in_sizes; (void)n_in; (void)out_size; (void)ws_size;
    const float* z_in   = (const float*)d_in[0];
    const float* in_w   = (const float*)d_in[1];
    const float* conv_w = (const float*)d_in[2];
    const float* conv_b = (const float*)d_in[3];
    const float* xp_w   = (const float*)d_in[4];
    const float* dt_w   = (const float*)d_in[5];
    const float* dt_b   = (const float*)d_in[6];
    const float* A_log  = (const float*)d_in[7];
    const float* D_par  = (const float*)d_in[8];
    const float* out_w  = (const float*)d_in[9];
    float* outp = (float*)d_out;

    char* p = (char*)d_ws;
    auto alloc = [&](size_t bytes) { char* r = p; p += (bytes + 255) & ~(size_t)255; return r; };
    unsigned* bar     = (unsigned*)alloc(256);
    u16* z_bf    = (u16*)alloc((size_t)BLROWS*DM*2);
    u16* z2_bf   = (u16*)alloc((size_t)BLROWS*DM*2);
    u16* xz_bf   = (u16*)alloc((size_t)BLROWS*1024*2);
    u16* xc_bf   = (u16*)alloc((size_t)BLROWS*DI*2);
    u16* y_bf    = (u16*)alloc((size_t)BLROWS*DI*2);
    u16* inw_bf  = (u16*)alloc((size_t)2*1024*256*2);
    u16* outw_bf = (u16*)alloc((size_t)2*256*512*2);
    u16* xpw_bf  = (u16*)alloc((size_t)2*64*512*2);
    float* x_dbl = (float*)alloc((size_t)BLROWS*64*4);
    u16* Pbuf    = (u16*)alloc((size_t)BATCH*NCH*DI*DS*2);
    u16* Sbuf    = (u16*)alloc((size_t)BATCH*NCH*DI*DS*2);
    float* Hbuf  = (float*)alloc((size_t)BATCH*NCH*DI*DS*4);

    /* weight casts */
    cast_f32_bf16_k<<<(2*1024*256)/256, 256, 0, stream>>>(in_w, inw_bf, 2*1024*256);
    cast_f32_bf16_k<<<(2*256*512)/256, 256, 0, stream>>>(out_w, outw_bf, 2*256*512);
    cast_xp_pad_k<<<(2*64*512)/256, 256, 0, stream>>>(xp_w, xpw_bf);
    /* activation cast only for layer-0 input */
    cast_f32_bf16_k<<<(BLROWS*DM)/256, 256, 0, stream>>>(z_in, z_bf, BLROWS*DM);

    const u16* zcur = z_bf;
    for (int l = 0; l < 2; ++l) {
        /* in_proj: xz_bf[8192,1024] = z @ in_w^T (bf16 out) */
        gemm_bt_k<<<dim3(BLROWS/64, 1024/64), 256, 0, stream>>>(
            (const __bf16*)zcur, (const __bf16*)(inw_bf + (size_t)l*1024*256),
            nullptr, xz_bf, BLROWS, 1024, 256);
        conv_silu_k<<<(BLROWS*DI)/256, 256, 0, stream>>>(
            xz_bf, conv_w + (size_t)l*DI*4, conv_b + (size_t)l*DI, xc_bf, bar);
        /* x_proj (padded to 64): x_dbl[8192,64] f32 */
        gemm_bt_k<<<dim3(BLROWS/64, 1), 256, 0, stream>>>(
            (const __bf16*)xc_bf, (const __bf16*)(xpw_bf + (size_t)l*64*512),
            x_dbl, nullptr, BLROWS, 64, 512);
        /* fused scan (A | stitch | C), includes dt computation */
        scan_fused_k<<<dim3(DI/128, NCH, BATCH), 256, 0, stream>>>(
            xc_bf, x_dbl, dt_w + (size_t)l*DI*DTR, dt_b + (size_t)l*DI,
            A_log + (size_t)l*DI*DS, D_par + (size_t)l*DI,
            xz_bf, Pbuf, Sbuf, Hbuf, y_bf, bar);
        /* out_proj: l0 -> bf16 z for next layer; l1 -> f32 d_out */
        gemm_bt_k<<<dim3(BLROWS/64, 256/64), 256, 0, stream>>>(
            (const __bf16*)y_bf, (const __bf16*)(outw_bf + (size_t)l*256*512),
            (l == 1) ? outp : nullptr, (l == 0) ? z2_bf : nullptr, BLROWS, 256, 512);
        zcur = z2_bf;
    }
}

// Round 4
// 372.036 us; speedup vs baseline: 1.7521x; 1.7521x over previous
//
#include <hip/hip_runtime.h>
#include <hip/hip_bf16.h>
#include <cstdint>
#include <cstddef>

#define DM   256
#define DI   512
#define DTR  16
#define DS   16
#define LSEQ 4096
#define BATCH 2
#define BLROWS (BATCH * LSEQ)   /* 8192 */
#define NCH  64                 /* chunks per sequence */
#define CLEN 64                 /* steps per chunk */

typedef __bf16 bf16x8 __attribute__((ext_vector_type(8)));
typedef float  f32x4  __attribute__((ext_vector_type(4)));
typedef unsigned short u16;
typedef u16 u16x8 __attribute__((ext_vector_type(8)));
typedef u16 u16x4 __attribute__((ext_vector_type(4)));

__device__ __forceinline__ u16 f2bfu(float f) {
    union { float f; unsigned u; } c; c.f = f;
    unsigned u = c.u;
    return (u16)((u + 0x7fffu + ((u >> 16) & 1u)) >> 16);
}
__device__ __forceinline__ float bfu2f(u16 u) {
    union { unsigned u; float f; } c; c.u = ((unsigned)u) << 16; return c.f;
}
__device__ __forceinline__ float siluf(float v) {
    return v * (1.0f / (1.0f + __expf(-v)));
}

/* ---------------- weight casts ---------------- */
__global__ __launch_bounds__(256) void cast_f32_bf16_k(
    const float* __restrict__ s, u16* __restrict__ d, int n) {
    int i = blockIdx.x * 256 + threadIdx.x;
    if (i < n) d[i] = f2bfu(s[i]);
}

/* pad x_proj_w [2,48,512] -> [2,64,512] bf16 (rows 48..63 zero) */
__global__ __launch_bounds__(256) void cast_xp_pad_k(
    const float* __restrict__ s, u16* __restrict__ d) {
    int i = blockIdx.x * 256 + threadIdx.x;     /* 2*64*512 = 65536 */
    int k = i & 511, o = (i >> 9) & 63, l = i >> 15;
    float v = (o < 48) ? s[(l * 48 + o) * 512 + k] : 0.0f;
    d[i] = f2bfu(v);
}

/* ---------------- bf16 MFMA GEMM: C[M,N] = A[M,K] * B[N,K]^T, f32/bf16 out ---- */
__global__ __launch_bounds__(256) void gemm_bt_k(
    const __bf16* __restrict__ A, const __bf16* __restrict__ B,
    float* __restrict__ Cf, u16* __restrict__ Cb, int M, int N, int K) {
    int tid  = threadIdx.x;
    int wave = tid >> 6, lane = tid & 63;
    int row  = lane & 15, q = lane >> 4;
    int bm = blockIdx.x * 64, bn = blockIdx.y * 64;
    int wm = bm + (wave & 1) * 32, wn = bn + (wave >> 1) * 32;
    f32x4 acc00 = {0.f,0.f,0.f,0.f}, acc01 = acc00, acc10 = acc00, acc11 = acc00;
    const bf16x8* Av = (const bf16x8*)A;
    const bf16x8* Bv = (const bf16x8*)B;
    int sK = K >> 3;
    for (int k0 = 0; k0 < K; k0 += 32) {
        int kb = (k0 >> 3) + q;
        bf16x8 a0 = Av[(size_t)(wm + row)      * sK + kb];
        bf16x8 a1 = Av[(size_t)(wm + 16 + row) * sK + kb];
        bf16x8 b0 = Bv[(size_t)(wn + row)      * sK + kb];
        bf16x8 b1 = Bv[(size_t)(wn + 16 + row) * sK + kb];
        acc00 = __builtin_amdgcn_mfma_f32_16x16x32_bf16(a0, b0, acc00, 0, 0, 0);
        acc01 = __builtin_amdgcn_mfma_f32_16x16x32_bf16(a0, b1, acc01, 0, 0, 0);
        acc10 = __builtin_amdgcn_mfma_f32_16x16x32_bf16(a1, b0, acc10, 0, 0, 0);
        acc11 = __builtin_amdgcn_mfma_f32_16x16x32_bf16(a1, b1, acc11, 0, 0, 0);
    }
    /* C/D layout: col = lane&15, row = q*4 + r */
    #pragma unroll
    for (int r = 0; r < 4; ++r) {
        size_t r0 = (size_t)(wm + q*4 + r) * N, r1 = (size_t)(wm + 16 + q*4 + r) * N;
        if (Cf) {
            Cf[r0 + wn + row]      = acc00[r];
            Cf[r0 + wn + 16 + row] = acc01[r];
            Cf[r1 + wn + row]      = acc10[r];
            Cf[r1 + wn + 16 + row] = acc11[r];
        }
        if (Cb) {
            Cb[r0 + wn + row]      = f2bfu(acc00[r]);
            Cb[r0 + wn + 16 + row] = f2bfu(acc01[r]);
            Cb[r1 + wn + row]      = f2bfu(acc10[r]);
            Cb[r1 + wn + 16 + row] = f2bfu(acc11[r]);
        }
    }
}

/* ---------------- causal depthwise conv (taps=4) + bias + silu, bf16 in/out --- */
__global__ __launch_bounds__(256) void conv_silu_k(
    const u16* __restrict__ xz, const float* __restrict__ cw,
    const float* __restrict__ cb, u16* __restrict__ xcb) {
    int i = blockIdx.x * 256 + threadIdx.x;   /* BLROWS*DI */
    int d = i & (DI - 1); int bl = i >> 9;
    int l = bl & (LSEQ - 1);
    float acc = cb[d];
    #pragma unroll
    for (int j = 0; j < 4; ++j) {
        int ll = l - 3 + j;
        if (ll >= 0) acc = fmaf(bfu2f(xz[(size_t)(bl - 3 + j) * (2*DI) + d]), cw[d*4 + j], acc);
    }
    xcb[i] = f2bfu(siluf(acc));
}

/* ---------------- scanA: per-chunk scan. grid (4, NCH, BATCH), 2 thr/d -------- */
/* computes dt (softplus) in-register, stores bf16 dt + bf16 P,S                  */
__global__ __launch_bounds__(256) void scanA_k(
    const u16* __restrict__ xcb, const float* __restrict__ xdbl,
    const float* __restrict__ dtw, const float* __restrict__ dtb,
    const float* __restrict__ Alog,
    u16* __restrict__ dtob, u16* __restrict__ Pb, u16* __restrict__ Sb) {
    __shared__ u16 xcs[CLEN * 128];        /* 16 KB */
    __shared__ float dt16s[CLEN * 16];     /* 4 KB */
    __shared__ float Bs[CLEN * 16];        /* 4 KB */
    int tid = threadIdx.x;
    int dg = blockIdx.x, c = blockIdx.y, b = blockIdx.z;
    int dLocal = tid >> 1, nh = tid & 1;
    int d = dg * 128 + dLocal;
    int bl0 = b * LSEQ + c * CLEN;

    /* stage xc slab [t][dLocal] */
    for (int idx = tid; idx < CLEN * 16; idx += 256)
        ((u16x8*)xcs)[idx] =
            ((const u16x8*)(xcb + (size_t)(bl0 + (idx >> 4)) * DI + dg * 128))[idx & 15];
    /* stage x_dbl cols 0..31 -> dt16s | Bs */
    for (int idx = tid; idx < CLEN * 8; idx += 256) {
        int row = idx >> 3, g = idx & 7;
        f32x4 v = ((const f32x4*)(xdbl + (size_t)(bl0 + row) * 64))[g];
        float* dst = (g < 4) ? &dt16s[row*16 + g*4] : &Bs[row*16 + (g-4)*4];
        *(f32x4*)dst = v;
    }
    float dtwr[16];
    {
        const f32x4* w4 = (const f32x4*)(dtw + (size_t)d * 16);
        #pragma unroll
        for (int g = 0; g < 4; ++g) { f32x4 v = w4[g];
            dtwr[g*4] = v[0]; dtwr[g*4+1] = v[1]; dtwr[g*4+2] = v[2]; dtwr[g*4+3] = v[3]; }
    }
    float dtbv = dtb[d];
    float Ac[8];
    {
        const f32x4* a4 = (const f32x4*)(Alog + (size_t)d * 16 + nh * 8);
        f32x4 a0 = a4[0], a1 = a4[1];
        #pragma unroll
        for (int j = 0; j < 4; ++j) { Ac[j] = -__expf(a0[j]); Ac[4+j] = -__expf(a1[j]); }
    }
    __syncthreads();

    float p[8], s[8];
    #pragma unroll
    for (int j = 0; j < 8; ++j) { p[j] = 1.0f; s[j] = 0.0f; }
    for (int t = 0; t < CLEN; ++t) {
        float acc = dtbv;
        #pragma unroll
        for (int r = 0; r < 16; ++r) acc = fmaf(dt16s[t*16 + r], dtwr[r], acc);
        float dt = (acc > 20.0f) ? acc : logf(1.0f + __expf(acc));
        if (nh == 0) dtob[(size_t)(bl0 + t) * DI + d] = f2bfu(dt);
        float xv = bfu2f(xcs[t*128 + dLocal]);
        float dx = dt * xv;
        #pragma unroll
        for (int j = 0; j < 8; ++j) {
            float a = __expf(dt * Ac[j]);
            s[j] = fmaf(a, s[j], Bs[t*16 + nh*8 + j] * dx);
            p[j] *= a;
        }
    }
    size_t base = ((size_t)(b*NCH + c) * DI + d) * 16 + nh * 8;
    u16x8 pv, sv;
    #pragma unroll
    for (int j = 0; j < 8; ++j) { pv[j] = f2bfu(p[j]); sv[j] = f2bfu(s[j]); }
    *(u16x8*)(Pb + base) = pv;
    *(u16x8*)(Sb + base) = sv;
}

/* ---------------- scanB: stitch chunk entry states (bf16 P,S -> f32 H) -------- */
__global__ __launch_bounds__(256) void scanB_k(
    const u16* __restrict__ Pb, const u16* __restrict__ Sb,
    float* __restrict__ H) {
    int i = blockIdx.x * 256 + threadIdx.x;   /* BATCH*DI*DS/4 = 4096 */
    int b = i >> 11, j4 = i & 2047;
    f32x4 h = {0.f, 0.f, 0.f, 0.f};
    for (int c = 0; c < NCH; ++c) {
        size_t i4 = (size_t)(b*NCH + c) * 2048 + j4;
        u16x4 pv = ((const u16x4*)Pb)[i4];
        u16x4 sv = ((const u16x4*)Sb)[i4];
        ((f32x4*)H)[i4] = h;
        #pragma unroll
        for (int j = 0; j < 4; ++j) h[j] = fmaf(bfu2f(pv[j]), h[j], bfu2f(sv[j]));
    }
}

/* ---------------- scanC: replay chunk from entry state, emit y*silu(gate) ----- */
__global__ __launch_bounds__(256) void scanC_k(
    const u16* __restrict__ xcb, const float* __restrict__ xdbl,
    const u16* __restrict__ dtob, const float* __restrict__ Alog,
    const float* __restrict__ Dp, const u16* __restrict__ xz,
    const float* __restrict__ H, u16* __restrict__ yout) {
    __shared__ u16 xcs[CLEN * 128];        /* 16 KB */
    __shared__ u16 dts[CLEN * 128];        /* 16 KB */
    __shared__ u16 gs[CLEN * 128];         /* 16 KB */
    __shared__ float Bs[CLEN * 16];        /* 4 KB */
    __shared__ float Cs[CLEN * 16];        /* 4 KB */
    int tid = threadIdx.x;
    int dg = blockIdx.x, c = blockIdx.y, b = blockIdx.z;
    int dLocal = tid >> 1, nh = tid & 1;
    int d = dg * 128 + dLocal;
    int bl0 = b * LSEQ + c * CLEN;

    for (int idx = tid; idx < CLEN * 16; idx += 256) {
        int row = idx >> 4, col = idx & 15;
        ((u16x8*)xcs)[idx] =
            ((const u16x8*)(xcb + (size_t)(bl0 + row) * DI + dg * 128))[col];
        ((u16x8*)dts)[idx] =
            ((const u16x8*)(dtob + (size_t)(bl0 + row) * DI + dg * 128))[col];
        ((u16x8*)gs)[idx] =
            ((const u16x8*)(xz + (size_t)(bl0 + row) * (2*DI) + DI + dg * 128))[col];
    }
    /* stage x_dbl cols 16..47 -> Bs | Cs */
    for (int idx = tid; idx < CLEN * 8; idx += 256) {
        int row = idx >> 3, g = idx & 7;
        f32x4 v = ((const f32x4*)(xdbl + (size_t)(bl0 + row) * 64))[g + 4];
        float* dst = (g < 4) ? &Bs[row*16 + g*4] : &Cs[row*16 + (g-4)*4];
        *(f32x4*)dst = v;
    }
    float Ac[8], h[8];
    {
        const f32x4* a4 = (const f32x4*)(Alog + (size_t)d * 16 + nh * 8);
        f32x4 a0 = a4[0], a1 = a4[1];
        const f32x4* h4 = (const f32x4*)(H + ((size_t)(b*NCH + c) * DI + d) * 16 + nh * 8);
        f32x4 h0 = h4[0], h1 = h4[1];
        #pragma unroll
        for (int j = 0; j < 4; ++j) {
            Ac[j] = -__expf(a0[j]); Ac[4+j] = -__expf(a1[j]);
            h[j] = h0[j]; h[4+j] = h1[j];
        }
    }
    float Dv = Dp[d];
    __syncthreads();

    for (int t = 0; t < CLEN; ++t) {
        float dt = bfu2f(dts[t*128 + dLocal]);
        float xv = bfu2f(xcs[t*128 + dLocal]);
        float dx = dt * xv;
        float y = 0.f;
        #pragma unroll
        for (int j = 0; j < 8; ++j) {
            float a = __expf(dt * Ac[j]);
            h[j] = fmaf(a, h[j], Bs[t*16 + nh*8 + j] * dx);
            y = fmaf(h[j], Cs[t*16 + nh*8 + j], y);
        }
        y += __shfl_xor(y, 1, 64);
        float gv = bfu2f(gs[t*128 + dLocal]);
        float yv = fmaf(xv, Dv, y) * siluf(gv);
        if (nh == 0) yout[(size_t)(bl0 + t) * DI + d] = f2bfu(yv);
    }
}

/* ================================================================== */
extern "C" void kernel_launch(void* const* d_in, const int* in_sizes, int n_in,
                              void* d_out, int out_size, void* d_ws, size_t ws_size,
                              hipStream_t stream) {
    (void)in_sizes; (void)n_in; (void)out_size; (void)ws_size;
    const float* z_in   = (const float*)d_in[0];
    const float* in_w   = (const float*)d_in[1];
    const float* conv_w = (const float*)d_in[2];
    const float* conv_b = (const float*)d_in[3];
    const float* xp_w   = (const float*)d_in[4];
    const float* dt_w   = (const float*)d_in[5];
    const float* dt_b   = (const float*)d_in[6];
    const float* A_log  = (const float*)d_in[7];
    const float* D_par  = (const float*)d_in[8];
    const float* out_w  = (const float*)d_in[9];
    float* outp = (float*)d_out;

    char* p = (char*)d_ws;
    auto alloc = [&](size_t bytes) { char* r = p; p += (bytes + 255) & ~(size_t)255; return r; };
    u16* z_bf    = (u16*)alloc((size_t)BLROWS*DM*2);
    u16* z2_bf   = (u16*)alloc((size_t)BLROWS*DM*2);
    u16* xz_bf   = (u16*)alloc((size_t)BLROWS*1024*2);
    u16* xc_bf   = (u16*)alloc((size_t)BLROWS*DI*2);
    u16* y_bf    = (u16*)alloc((size_t)BLROWS*DI*2);
    u16* dt_bf   = (u16*)alloc((size_t)BLROWS*DI*2);
    u16* inw_bf  = (u16*)alloc((size_t)2*1024*256*2);
    u16* outw_bf = (u16*)alloc((size_t)2*256*512*2);
    u16* xpw_bf  = (u16*)alloc((size_t)2*64*512*2);
    float* x_dbl = (float*)alloc((size_t)BLROWS*64*4);
    u16* Pbuf    = (u16*)alloc((size_t)BATCH*NCH*DI*DS*2);
    u16* Sbuf    = (u16*)alloc((size_t)BATCH*NCH*DI*DS*2);
    float* Hbuf  = (float*)alloc((size_t)BATCH*NCH*DI*DS*4);

    /* weight casts + layer-0 activation cast */
    cast_f32_bf16_k<<<(2*1024*256)/256, 256, 0, stream>>>(in_w, inw_bf, 2*1024*256);
    cast_f32_bf16_k<<<(2*256*512)/256, 256, 0, stream>>>(out_w, outw_bf, 2*256*512);
    cast_xp_pad_k<<<(2*64*512)/256, 256, 0, stream>>>(xp_w, xpw_bf);
    cast_f32_bf16_k<<<(BLROWS*DM)/256, 256, 0, stream>>>(z_in, z_bf, BLROWS*DM);

    const u16* zcur = z_bf;
    for (int l = 0; l < 2; ++l) {
        /* in_proj: xz_bf[8192,1024] = z @ in_w^T (bf16 out) */
        gemm_bt_k<<<dim3(BLROWS/64, 1024/64), 256, 0, stream>>>(
            (const __bf16*)zcur, (const __bf16*)(inw_bf + (size_t)l*1024*256),
            nullptr, xz_bf, BLROWS, 1024, 256);
        conv_silu_k<<<(BLROWS*DI)/256, 256, 0, stream>>>(
            xz_bf, conv_w + (size_t)l*DI*4, conv_b + (size_t)l*DI, xc_bf);
        /* x_proj (padded to 64): x_dbl[8192,64] f32 */
        gemm_bt_k<<<dim3(BLROWS/64, 1), 256, 0, stream>>>(
            (const __bf16*)xc_bf, (const __bf16*)(xpw_bf + (size_t)l*64*512),
            x_dbl, nullptr, BLROWS, 64, 512);
        scanA_k<<<dim3(DI/128, NCH, BATCH), 256, 0, stream>>>(
            xc_bf, x_dbl, dt_w + (size_t)l*DI*DTR, dt_b + (size_t)l*DI,
            A_log + (size_t)l*DI*DS, dt_bf, Pbuf, Sbuf);
        scanB_k<<<(BATCH*DI*DS/4)/256, 256, 0, stream>>>(Pbuf, Sbuf, Hbuf);
        scanC_k<<<dim3(DI/128, NCH, BATCH), 256, 0, stream>>>(
            xc_bf, x_dbl, dt_bf, A_log + (size_t)l*DI*DS,
            D_par + (size_t)l*DI, xz_bf, Hbuf, y_bf);
        /* out_proj: l0 -> bf16 z for next layer; l1 -> f32 d_out */
        gemm_bt_k<<<dim3(BLROWS/64, 256/64), 256, 0, stream>>>(
            (const __bf16*)y_bf, (const __bf16*)(outw_bf + (size_t)l*256*512),
            (l == 1) ? outp : nullptr, (l == 0) ? z2_bf : nullptr, BLROWS, 256, 512);
        zcur = z2_bf;
    }
}

// Round 5
// 327.295 us; speedup vs baseline: 1.9916x; 1.1367x over previous
//
#include <hip/hip_runtime.h>
#include <hip/hip_bf16.h>
#include <cstdint>
#include <cstddef>

#define DM   256
#define DI   512
#define DTR  16
#define DS   16
#define LSEQ 4096
#define BATCH 2
#define BLROWS (BATCH * LSEQ)   /* 8192 */
#define NCH  64                 /* chunks per sequence */
#define CLEN 64                 /* steps per chunk */

#define BM 128
#define BK 32

typedef __bf16 bf16x8 __attribute__((ext_vector_type(8)));
typedef float  f32x4  __attribute__((ext_vector_type(4)));
typedef unsigned short u16;
typedef u16 u16x8 __attribute__((ext_vector_type(8)));
typedef u16 u16x4 __attribute__((ext_vector_type(4)));

__device__ __forceinline__ u16 f2bfu(float f) {
    union { float f; unsigned u; } c; c.f = f;
    unsigned u = c.u;
    return (u16)((u + 0x7fffu + ((u >> 16) & 1u)) >> 16);
}
__device__ __forceinline__ float bfu2f(u16 u) {
    union { unsigned u; float f; } c; c.u = ((unsigned)u) << 16; return c.f;
}
__device__ __forceinline__ float siluf(float v) {
    return v * (1.0f / (1.0f + __expf(-v)));
}

/* async global->LDS, 16B per lane; lds dest = wave-uniform base + lane*16 */
__device__ __forceinline__ void gload_lds16(const void* g, void* l) {
    __builtin_amdgcn_global_load_lds(
        (const __attribute__((address_space(1))) unsigned int*)g,
        (__attribute__((address_space(3))) unsigned int*)l, 16, 0, 0);
}

/* ---------------- merged startup casts ---------------- */
#define N_INW  (2*1024*256)            /* 524288 */
#define N_OUTW (2*256*512)             /* 262144 */
#define N_XPW  (2*64*512)              /* 65536 */
#define N_Z    (BLROWS*DM)             /* 2097152 */
__global__ __launch_bounds__(256) void cast_all_k(
    const float* __restrict__ in_w, const float* __restrict__ out_w,
    const float* __restrict__ xp_w, const float* __restrict__ z,
    u16* __restrict__ inw_bf, u16* __restrict__ outw_bf,
    u16* __restrict__ xpw_bf, u16* __restrict__ z_bf) {
    int i = blockIdx.x * 256 + threadIdx.x;
    if (i < N_INW) {
        inw_bf[i] = f2bfu(in_w[i]);
    } else if (i < N_INW + N_OUTW) {
        int j = i - N_INW;
        outw_bf[j] = f2bfu(out_w[j]);
    } else if (i < N_INW + N_OUTW + N_XPW) {
        int j = i - (N_INW + N_OUTW);
        int k = j & 511, o = (j >> 9) & 63, l = j >> 15;
        xpw_bf[j] = f2bfu((o < 48) ? xp_w[(l * 48 + o) * 512 + k] : 0.0f);
    } else {
        int j = i - (N_INW + N_OUTW + N_XPW);
        z_bf[j] = f2bfu(z[j]);
    }
}

/* ---------------- LDS-staged bf16 MFMA GEMM (m97 pattern) --------------------- */
/* C[M,N] = A[M,K] * B[N,K]^T.  Block tile BM=128 x BN, BK=32, 256 threads.      */
/* Wave grid WGM x (4/WGM); wave tile (MT*16) x (NT*16).                          */
template<int BN, int WGM, int MT, int NT>
__global__ __launch_bounds__(256) void gemm_lds_k(
    const __bf16* __restrict__ A, const __bf16* __restrict__ B,
    float* __restrict__ Cf, u16* __restrict__ Cb, int M, int N, int K) {
    __shared__ __bf16 As[BM * BK];
    __shared__ __bf16 Bs[BN * BK];
    int tid = threadIdx.x, wave = tid >> 6, lane = tid & 63;
    int bm = blockIdx.x * BM, bn = blockIdx.y * BN;
    int wm = (wave % WGM) * (MT * 16);
    int wn = (wave / WGM) * (NT * 16);
    int row = lane & 15, q = lane >> 4;
    int srow = lane >> 2, sseg = lane & 3;       /* staging: 16 rows x 4 x 8 elems */
    f32x4 acc[MT][NT] = {};

    for (int k0 = 0; k0 < K; k0 += BK) {
        /* stage A tile: rows bm..bm+127, cols k0..k0+31 */
        #pragma unroll
        for (int i = 0; i < BM / 64; ++i) {
            int r0 = wave * (BM / 4) + i * 16;
            gload_lds16(A + (size_t)(bm + r0 + srow) * K + k0 + sseg * 8,
                        As + r0 * BK);
        }
        /* stage B tile: rows bn..bn+BN-1 */
        #pragma unroll
        for (int i = 0; i < BN / 64; ++i) {
            int r0 = wave * (BN / 4) + i * 16;
            gload_lds16(B + (size_t)(bn + r0 + srow) * K + k0 + sseg * 8,
                        Bs + r0 * BK);
        }
        __syncthreads();
        bf16x8 af[MT], bfr[NT];
        #pragma unroll
        for (int mi = 0; mi < MT; ++mi)
            af[mi] = *(const bf16x8*)&As[(wm + mi*16 + row) * BK + q * 8];
        #pragma unroll
        for (int ni = 0; ni < NT; ++ni)
            bfr[ni] = *(const bf16x8*)&Bs[(wn + ni*16 + row) * BK + q * 8];
        #pragma unroll
        for (int mi = 0; mi < MT; ++mi)
            #pragma unroll
            for (int ni = 0; ni < NT; ++ni)
                acc[mi][ni] = __builtin_amdgcn_mfma_f32_16x16x32_bf16(
                    af[mi], bfr[ni], acc[mi][ni], 0, 0, 0);
        __syncthreads();
    }
    /* C/D layout: col = lane&15, row = q*4 + r */
    #pragma unroll
    for (int mi = 0; mi < MT; ++mi) {
        #pragma unroll
        for (int r = 0; r < 4; ++r) {
            size_t gr = (size_t)(bm + wm + mi*16 + q*4 + r) * N;
            #pragma unroll
            for (int ni = 0; ni < NT; ++ni) {
                int gc = bn + wn + ni*16 + row;
                if (Cf) Cf[gr + gc] = acc[mi][ni][r];
                if (Cb) Cb[gr + gc] = f2bfu(acc[mi][ni][r]);
            }
        }
    }
}

/* ---------------- causal depthwise conv (taps=4) + bias + silu, bf16 in/out --- */
__global__ __launch_bounds__(256) void conv_silu_k(
    const u16* __restrict__ xz, const float* __restrict__ cw,
    const float* __restrict__ cb, u16* __restrict__ xcb) {
    int i = blockIdx.x * 256 + threadIdx.x;   /* BLROWS*DI */
    int d = i & (DI - 1); int bl = i >> 9;
    int l = bl & (LSEQ - 1);
    float acc = cb[d];
    #pragma unroll
    for (int j = 0; j < 4; ++j) {
        int ll = l - 3 + j;
        if (ll >= 0) acc = fmaf(bfu2f(xz[(size_t)(bl - 3 + j) * (2*DI) + d]), cw[d*4 + j], acc);
    }
    xcb[i] = f2bfu(siluf(acc));
}

/* ---------------- scanA: per-chunk scan. grid (4, NCH, BATCH), 2 thr/d -------- */
__global__ __launch_bounds__(256) void scanA_k(
    const u16* __restrict__ xcb, const float* __restrict__ xdbl,
    const float* __restrict__ dtw, const float* __restrict__ dtb,
    const float* __restrict__ Alog,
    u16* __restrict__ dtob, u16* __restrict__ Pb, u16* __restrict__ Sb) {
    __shared__ u16 xcs[CLEN * 128];        /* 16 KB */
    __shared__ float dt16s[CLEN * 16];     /* 4 KB */
    __shared__ float Bs2[CLEN * 16];       /* 4 KB */
    int tid = threadIdx.x;
    int dg = blockIdx.x, c = blockIdx.y, b = blockIdx.z;
    int dLocal = tid >> 1, nh = tid & 1;
    int d = dg * 128 + dLocal;
    int bl0 = b * LSEQ + c * CLEN;

    for (int idx = tid; idx < CLEN * 16; idx += 256)
        ((u16x8*)xcs)[idx] =
            ((const u16x8*)(xcb + (size_t)(bl0 + (idx >> 4)) * DI + dg * 128))[idx & 15];
    for (int idx = tid; idx < CLEN * 8; idx += 256) {
        int rrow = idx >> 3, g = idx & 7;
        f32x4 v = ((const f32x4*)(xdbl + (size_t)(bl0 + rrow) * 64))[g];
        float* dst = (g < 4) ? &dt16s[rrow*16 + g*4] : &Bs2[rrow*16 + (g-4)*4];
        *(f32x4*)dst = v;
    }
    float dtwr[16];
    {
        const f32x4* w4 = (const f32x4*)(dtw + (size_t)d * 16);
        #pragma unroll
        for (int g = 0; g < 4; ++g) { f32x4 v = w4[g];
            dtwr[g*4] = v[0]; dtwr[g*4+1] = v[1]; dtwr[g*4+2] = v[2]; dtwr[g*4+3] = v[3]; }
    }
    float dtbv = dtb[d];
    float Ac[8];
    {
        const f32x4* a4 = (const f32x4*)(Alog + (size_t)d * 16 + nh * 8);
        f32x4 a0 = a4[0], a1 = a4[1];
        #pragma unroll
        for (int j = 0; j < 4; ++j) { Ac[j] = -__expf(a0[j]); Ac[4+j] = -__expf(a1[j]); }
    }
    __syncthreads();

    float p[8], s[8];
    #pragma unroll
    for (int j = 0; j < 8; ++j) { p[j] = 1.0f; s[j] = 0.0f; }
    for (int t = 0; t < CLEN; ++t) {
        float acc = dtbv;
        #pragma unroll
        for (int r = 0; r < 16; ++r) acc = fmaf(dt16s[t*16 + r], dtwr[r], acc);
        float dt = (acc > 20.0f) ? acc : logf(1.0f + __expf(acc));
        if (nh == 0) dtob[(size_t)(bl0 + t) * DI + d] = f2bfu(dt);
        float xv = bfu2f(xcs[t*128 + dLocal]);
        float dx = dt * xv;
        #pragma unroll
        for (int j = 0; j < 8; ++j) {
            float a = __expf(dt * Ac[j]);
            s[j] = fmaf(a, s[j], Bs2[t*16 + nh*8 + j] * dx);
            p[j] *= a;
        }
    }
    size_t base = ((size_t)(b*NCH + c) * DI + d) * 16 + nh * 8;
    u16x8 pv, sv;
    #pragma unroll
    for (int j = 0; j < 8; ++j) { pv[j] = f2bfu(p[j]); sv[j] = f2bfu(s[j]); }
    *(u16x8*)(Pb + base) = pv;
    *(u16x8*)(Sb + base) = sv;
}

/* ---------------- scanB: stitch chunk entry states (bf16 P,S -> f32 H) -------- */
__global__ __launch_bounds__(256) void scanB_k(
    const u16* __restrict__ Pb, const u16* __restrict__ Sb,
    float* __restrict__ H) {
    int i = blockIdx.x * 256 + threadIdx.x;   /* BATCH*DI*DS/4 = 4096 */
    int b = i >> 11, j4 = i & 2047;
    f32x4 h = {0.f, 0.f, 0.f, 0.f};
    for (int c = 0; c < NCH; ++c) {
        size_t i4 = (size_t)(b*NCH + c) * 2048 + j4;
        u16x4 pv = ((const u16x4*)Pb)[i4];
        u16x4 sv = ((const u16x4*)Sb)[i4];
        ((f32x4*)H)[i4] = h;
        #pragma unroll
        for (int j = 0; j < 4; ++j) h[j] = fmaf(bfu2f(pv[j]), h[j], bfu2f(sv[j]));
    }
}

/* ---------------- scanC: replay chunk from entry state, emit y*silu(gate) ----- */
__global__ __launch_bounds__(256) void scanC_k(
    const u16* __restrict__ xcb, const float* __restrict__ xdbl,
    const u16* __restrict__ dtob, const float* __restrict__ Alog,
    const float* __restrict__ Dp, const u16* __restrict__ xz,
    const float* __restrict__ H, u16* __restrict__ yout) {
    __shared__ u16 xcs[CLEN * 128];        /* 16 KB */
    __shared__ u16 dts[CLEN * 128];        /* 16 KB */
    __shared__ u16 gs[CLEN * 128];         /* 16 KB */
    __shared__ float Bs2[CLEN * 16];       /* 4 KB */
    __shared__ float Cs2[CLEN * 16];       /* 4 KB */
    int tid = threadIdx.x;
    int dg = blockIdx.x, c = blockIdx.y, b = blockIdx.z;
    int dLocal = tid >> 1, nh = tid & 1;
    int d = dg * 128 + dLocal;
    int bl0 = b * LSEQ + c * CLEN;

    for (int idx = tid; idx < CLEN * 16; idx += 256) {
        int rrow = idx >> 4, col = idx & 15;
        ((u16x8*)xcs)[idx] =
            ((const u16x8*)(xcb + (size_t)(bl0 + rrow) * DI + dg * 128))[col];
        ((u16x8*)dts)[idx] =
            ((const u16x8*)(dtob + (size_t)(bl0 + rrow) * DI + dg * 128))[col];
        ((u16x8*)gs)[idx] =
            ((const u16x8*)(xz + (size_t)(bl0 + rrow) * (2*DI) + DI + dg * 128))[col];
    }
    for (int idx = tid; idx < CLEN * 8; idx += 256) {
        int rrow = idx >> 3, g = idx & 7;
        f32x4 v = ((const f32x4*)(xdbl + (size_t)(bl0 + rrow) * 64))[g + 4];
        float* dst = (g < 4) ? &Bs2[rrow*16 + g*4] : &Cs2[rrow*16 + (g-4)*4];
        *(f32x4*)dst = v;
    }
    float Ac[8], h[8];
    {
        const f32x4* a4 = (const f32x4*)(Alog + (size_t)d * 16 + nh * 8);
        f32x4 a0 = a4[0], a1 = a4[1];
        const f32x4* h4 = (const f32x4*)(H + ((size_t)(b*NCH + c) * DI + d) * 16 + nh * 8);
        f32x4 h0 = h4[0], h1 = h4[1];
        #pragma unroll
        for (int j = 0; j < 4; ++j) {
            Ac[j] = -__expf(a0[j]); Ac[4+j] = -__expf(a1[j]);
            h[j] = h0[j]; h[4+j] = h1[j];
        }
    }
    float Dv = Dp[d];
    __syncthreads();

    for (int t = 0; t < CLEN; ++t) {
        float dt = bfu2f(dts[t*128 + dLocal]);
        float xv = bfu2f(xcs[t*128 + dLocal]);
        float dx = dt * xv;
        float y = 0.f;
        #pragma unroll
        for (int j = 0; j < 8; ++j) {
            float a = __expf(dt * Ac[j]);
            h[j] = fmaf(a, h[j], Bs2[t*16 + nh*8 + j] * dx);
            y = fmaf(h[j], Cs2[t*16 + nh*8 + j], y);
        }
        y += __shfl_xor(y, 1, 64);
        float gv = bfu2f(gs[t*128 + dLocal]);
        float yv = fmaf(xv, Dv, y) * siluf(gv);
        if (nh == 0) yout[(size_t)(bl0 + t) * DI + d] = f2bfu(yv);
    }
}

/* ================================================================== */
extern "C" void kernel_launch(void* const* d_in, const int* in_sizes, int n_in,
                              void* d_out, int out_size, void* d_ws, size_t ws_size,
                              hipStream_t stream) {
    (void)in_sizes; (void)n_in; (void)out_size; (void)ws_size;
    const float* z_in   = (const float*)d_in[0];
    const float* in_w   = (const float*)d_in[1];
    const float* conv_w = (const float*)d_in[2];
    const float* conv_b = (const float*)d_in[3];
    const float* xp_w   = (const float*)d_in[4];
    const float* dt_w   = (const float*)d_in[5];
    const float* dt_b   = (const float*)d_in[6];
    const float* A_log  = (const float*)d_in[7];
    const float* D_par  = (const float*)d_in[8];
    const float* out_w  = (const float*)d_in[9];
    float* outp = (float*)d_out;

    char* p = (char*)d_ws;
    auto alloc = [&](size_t bytes) { char* r = p; p += (bytes + 255) & ~(size_t)255; return r; };
    u16* z_bf    = (u16*)alloc((size_t)BLROWS*DM*2);
    u16* z2_bf   = (u16*)alloc((size_t)BLROWS*DM*2);
    u16* xz_bf   = (u16*)alloc((size_t)BLROWS*1024*2);
    u16* xc_bf   = (u16*)alloc((size_t)BLROWS*DI*2);
    u16* y_bf    = (u16*)alloc((size_t)BLROWS*DI*2);
    u16* dt_bf   = (u16*)alloc((size_t)BLROWS*DI*2);
    u16* inw_bf  = (u16*)alloc((size_t)2*1024*256*2);
    u16* outw_bf = (u16*)alloc((size_t)2*256*512*2);
    u16* xpw_bf  = (u16*)alloc((size_t)2*64*512*2);
    float* x_dbl = (float*)alloc((size_t)BLROWS*64*4);
    u16* Pbuf    = (u16*)alloc((size_t)BATCH*NCH*DI*DS*2);
    u16* Sbuf    = (u16*)alloc((size_t)BATCH*NCH*DI*DS*2);
    float* Hbuf  = (float*)alloc((size_t)BATCH*NCH*DI*DS*4);

    /* merged weight + layer-0 activation casts */
    cast_all_k<<<(N_INW + N_OUTW + N_XPW + N_Z)/256, 256, 0, stream>>>(
        in_w, out_w, xp_w, z_in, inw_bf, outw_bf, xpw_bf, z_bf);

    const u16* zcur = z_bf;
    for (int l = 0; l < 2; ++l) {
        /* in_proj: xz_bf[8192,1024] = z @ in_w^T (bf16 out) */
        gemm_lds_k<128,2,4,4><<<dim3(BLROWS/128, 1024/128), 256, 0, stream>>>(
            (const __bf16*)zcur, (const __bf16*)(inw_bf + (size_t)l*1024*256),
            nullptr, xz_bf, BLROWS, 1024, 256);
        conv_silu_k<<<(BLROWS*DI)/256, 256, 0, stream>>>(
            xz_bf, conv_w + (size_t)l*DI*4, conv_b + (size_t)l*DI, xc_bf);
        /* x_proj (padded to 64): x_dbl[8192,64] f32 */
        gemm_lds_k<64,4,2,4><<<dim3(BLROWS/128, 1), 256, 0, stream>>>(
            (const __bf16*)xc_bf, (const __bf16*)(xpw_bf + (size_t)l*64*512),
            x_dbl, nullptr, BLROWS, 64, 512);
        scanA_k<<<dim3(DI/128, NCH, BATCH), 256, 0, stream>>>(
            xc_bf, x_dbl, dt_w + (size_t)l*DI*DTR, dt_b + (size_t)l*DI,
            A_log + (size_t)l*DI*DS, dt_bf, Pbuf, Sbuf);
        scanB_k<<<(BATCH*DI*DS/4)/256, 256, 0, stream>>>(Pbuf, Sbuf, Hbuf);
        scanC_k<<<dim3(DI/128, NCH, BATCH), 256, 0, stream>>>(
            xc_bf, x_dbl, dt_bf, A_log + (size_t)l*DI*DS,
            D_par + (size_t)l*DI, xz_bf, Hbuf, y_bf);
        /* out_proj: l0 -> bf16 z for next layer; l1 -> f32 d_out */
        gemm_lds_k<128,2,4,4><<<dim3(BLROWS/128, 256/128), 256, 0, stream>>>(
            (const __bf16*)y_bf, (const __bf16*)(outw_bf + (size_t)l*256*512),
            (l == 1) ? outp : nullptr, (l == 0) ? z2_bf : nullptr, BLROWS, 256, 512);
        zcur = z2_bf;
    }
}

// Round 6
// 255.058 us; speedup vs baseline: 2.5556x; 1.2832x over previous
//
#include <hip/hip_runtime.h>
#include <hip/hip_bf16.h>
#include <cstdint>
#include <cstddef>

#define DM   256
#define DI   512
#define DS   16
#define LSEQ 4096
#define BATCH 2
#define BLROWS (BATCH * LSEQ)   /* 8192 */
#define NCH  128                /* chunks per sequence */
#define CLEN 32                 /* steps per chunk */
#define XCP  520                /* padded LDS row stride (u16) for MFMA A reads */

typedef __bf16 bf16x8 __attribute__((ext_vector_type(8)));
typedef float  f32x4  __attribute__((ext_vector_type(4)));
typedef unsigned short u16;
typedef u16 u16x8 __attribute__((ext_vector_type(8)));
typedef u16 u16x4 __attribute__((ext_vector_type(4)));

__device__ __forceinline__ u16 f2bfu(float f) {
    union { float f; unsigned u; } c; c.f = f;
    unsigned u = c.u;
    return (u16)((u + 0x7fffu + ((u >> 16) & 1u)) >> 16);
}
__device__ __forceinline__ float bfu2f(u16 u) {
    union { unsigned u; float f; } c; c.u = ((unsigned)u) << 16; return c.f;
}
__device__ __forceinline__ float siluf(float v) {
    return v * (1.0f / (1.0f + __expf(-v)));
}
__device__ __forceinline__ void gload_lds16(const void* g, void* l) {
    __builtin_amdgcn_global_load_lds(
        (const __attribute__((address_space(1))) unsigned int*)g,
        (__attribute__((address_space(3))) unsigned int*)l, 16, 0, 0);
}

/* ---------------- merged startup casts ---------------- */
#define N_INW  (2*1024*256)
#define N_OUTW (2*256*512)
#define N_XPW  (2*64*512)
#define N_Z    (BLROWS*DM)
__global__ __launch_bounds__(256) void cast_all_k(
    const float* __restrict__ in_w, const float* __restrict__ out_w,
    const float* __restrict__ xp_w, const float* __restrict__ z,
    u16* __restrict__ inw_bf, u16* __restrict__ outw_bf,
    u16* __restrict__ xpw_bf, u16* __restrict__ z_bf) {
    int i = blockIdx.x * 256 + threadIdx.x;
    if (i < N_INW) {
        inw_bf[i] = f2bfu(in_w[i]);
    } else if (i < N_INW + N_OUTW) {
        int j = i - N_INW;
        outw_bf[j] = f2bfu(out_w[j]);
    } else if (i < N_INW + N_OUTW + N_XPW) {
        int j = i - (N_INW + N_OUTW);
        int k = j & 511, o = (j >> 9) & 63, l = j >> 15;
        xpw_bf[j] = f2bfu((o < 48) ? xp_w[(l * 48 + o) * 512 + k] : 0.0f);
    } else {
        int j = i - (N_INW + N_OUTW + N_XPW);
        z_bf[j] = f2bfu(z[j]);
    }
}

/* ---------------- in_proj: LDS-staged bf16 MFMA GEMM (m97 pattern) ------------ */
/* C[M,N] = A[M,K] * B[N,K]^T. 128x128 tile, BK=32, 256 thr, bf16 out. */
__global__ __launch_bounds__(256) void gemm_in_k(
    const __bf16* __restrict__ A, const __bf16* __restrict__ B,
    u16* __restrict__ Cb, int M, int N, int K) {
    __shared__ __bf16 As[128 * 32];
    __shared__ __bf16 Bs[128 * 32];
    int tid = threadIdx.x, wave = tid >> 6, lane = tid & 63;
    int bm = blockIdx.x * 128, bn = blockIdx.y * 128;
    int wm = (wave & 1) * 64, wn = (wave >> 1) * 64;
    int row = lane & 15, q = lane >> 4;
    int srow = lane >> 2, sseg = lane & 3;
    f32x4 acc[4][4] = {};
    for (int k0 = 0; k0 < K; k0 += 32) {
        #pragma unroll
        for (int i = 0; i < 2; ++i) {
            int r0 = wave * 32 + i * 16;
            gload_lds16(A + (size_t)(bm + r0 + srow) * K + k0 + sseg * 8, As + r0 * 32);
            gload_lds16(B + (size_t)(bn + r0 + srow) * K + k0 + sseg * 8, Bs + r0 * 32);
        }
        __syncthreads();
        bf16x8 af[4], bfr[4];
        #pragma unroll
        for (int mi = 0; mi < 4; ++mi)
            af[mi] = *(const bf16x8*)&As[(wm + mi*16 + row) * 32 + q * 8];
        #pragma unroll
        for (int ni = 0; ni < 4; ++ni)
            bfr[ni] = *(const bf16x8*)&Bs[(wn + ni*16 + row) * 32 + q * 8];
        #pragma unroll
        for (int mi = 0; mi < 4; ++mi)
            #pragma unroll
            for (int ni = 0; ni < 4; ++ni)
                acc[mi][ni] = __builtin_amdgcn_mfma_f32_16x16x32_bf16(
                    af[mi], bfr[ni], acc[mi][ni], 0, 0, 0);
        __syncthreads();
    }
    #pragma unroll
    for (int mi = 0; mi < 4; ++mi)
        #pragma unroll
        for (int r = 0; r < 4; ++r) {
            size_t gr = (size_t)(bm + wm + mi*16 + q*4 + r) * N;
            #pragma unroll
            for (int ni = 0; ni < 4; ++ni)
                Cb[gr + bn + wn + ni*16 + row] = f2bfu(acc[mi][ni][r]);
        }
}

/* ---------------- fused A: conv+silu -> x_proj MFMA -> dt -> chunk scan ------- */
/* grid (NCH, BATCH), 512 threads (8 waves). One block = one chunk, all 512 ch.  */
__global__ __launch_bounds__(512) void fused_a_k(
    const u16* __restrict__ xz, const float* __restrict__ cw,
    const float* __restrict__ cb, const __bf16* __restrict__ xpw,
    const float* __restrict__ dtw, const float* __restrict__ dtb,
    const float* __restrict__ Alog,
    u16* __restrict__ xcb, u16* __restrict__ dtob,
    float* __restrict__ BCg, u16* __restrict__ Pb, u16* __restrict__ Sb) {
    __shared__ u16 xc_s[CLEN * XCP];       /* 33.3 KB */
    __shared__ float xd_s[CLEN * 68];      /* 8.7 KB */
    int tid = threadIdx.x;
    int c = blockIdx.x, b = blockIdx.y;
    int bl0 = b * LSEQ + c * CLEN;
    int d = tid;

    /* phase 1: causal depthwise conv + bias + silu (thread = channel) */
    {
        float w0 = cw[d*4], w1 = cw[d*4+1], w2 = cw[d*4+2], w3 = cw[d*4+3];
        float bias = cb[d];
        float xm3 = 0.f, xm2 = 0.f, xm1 = 0.f;
        int l0 = c * CLEN;
        if (l0 - 3 >= 0) xm3 = bfu2f(xz[(size_t)(bl0 - 3) * 1024 + d]);
        if (l0 - 2 >= 0) xm2 = bfu2f(xz[(size_t)(bl0 - 2) * 1024 + d]);
        if (l0 - 1 >= 0) xm1 = bfu2f(xz[(size_t)(bl0 - 1) * 1024 + d]);
        #pragma unroll 4
        for (int t = 0; t < CLEN; ++t) {
            float xcur = bfu2f(xz[(size_t)(bl0 + t) * 1024 + d]);
            float acc = fmaf(w0, xm3, fmaf(w1, xm2, fmaf(w2, xm1, fmaf(w3, xcur, bias))));
            float v = siluf(acc);
            u16 vb = f2bfu(v);
            xc_s[t * XCP + d] = vb;
            xcb[(size_t)(bl0 + t) * DI + d] = vb;
            xm3 = xm2; xm2 = xm1; xm1 = xcur;
        }
    }
    __syncthreads();

    /* phase 2: x_proj  xd[32,64] = xc_s[32,512] @ xpw[64,512]^T  (8 waves) */
    {
        int wave = tid >> 6, lane = tid & 63;
        int row = lane & 15, q = lane >> 4;
        int mt = wave & 1, nt = wave >> 2;         /* use waves 0..7: mt 2 x nt... */
        /* assign: wave w -> mt = w&1, ntile = w>>1 (0..3) */
        nt = wave >> 1;
        f32x4 acc = {0.f, 0.f, 0.f, 0.f};
        #pragma unroll
        for (int kb = 0; kb < 16; ++kb) {
            bf16x8 a = *(const bf16x8*)&xc_s[(mt*16 + row) * XCP + kb*32 + q*8];
            bf16x8 bb = *(const bf16x8*)(xpw + (size_t)(nt*16 + row) * 512 + kb*32 + q*8);
            acc = __builtin_amdgcn_mfma_f32_16x16x32_bf16(a, bb, acc, 0, 0, 0);
        }
        #pragma unroll
        for (int r = 0; r < 4; ++r)
            xd_s[(mt*16 + q*4 + r) * 68 + nt*16 + row] = acc[r];
    }
    __syncthreads();

    /* store compact B,C (cols 16..47) for scanC */
    for (int i = tid; i < CLEN * 32; i += 512) {
        int t = i >> 5, cc = i & 31;
        BCg[((size_t)(b*NCH + c) * CLEN + t) * 32 + cc] = xd_s[t*68 + 16 + cc];
    }

    /* phase 3: dt = softplus(xd[:, :16] @ dtw^T + dtb); chunk scan -> P,S */
    {
        float dtwr[16];
        const f32x4* w4 = (const f32x4*)(dtw + (size_t)d * 16);
        #pragma unroll
        for (int g = 0; g < 4; ++g) { f32x4 v = w4[g];
            dtwr[g*4] = v[0]; dtwr[g*4+1] = v[1]; dtwr[g*4+2] = v[2]; dtwr[g*4+3] = v[3]; }
        float dtbv = dtb[d];
        float Ac[16];
        const f32x4* a4 = (const f32x4*)(Alog + (size_t)d * 16);
        #pragma unroll
        for (int g = 0; g < 4; ++g) { f32x4 v = a4[g];
            #pragma unroll
            for (int j = 0; j < 4; ++j) Ac[g*4+j] = -__expf(v[j]); }
        bool fastp = true;
        #pragma unroll
        for (int n = 1; n < 16; ++n)
            fastp = fastp && (fabsf(Ac[n] - (float)(n+1) * Ac[0])
                              <= 1e-4f * fabsf(Ac[n]));
        float p[16], s[16];
        #pragma unroll
        for (int n = 0; n < 16; ++n) { p[n] = 1.0f; s[n] = 0.0f; }
        for (int t = 0; t < CLEN; ++t) {
            float acc = dtbv;
            #pragma unroll
            for (int r = 0; r < 16; ++r) acc = fmaf(xd_s[t*68 + r], dtwr[r], acc);
            float dtv = (acc > 20.0f) ? acc : logf(1.0f + __expf(acc));
            dtob[(size_t)(bl0 + t) * DI + d] = f2bfu(dtv);
            float xv = bfu2f(xc_s[t * XCP + d]);
            float dx = dtv * xv;
            float an[16];
            if (fastp) {
                float a0 = __expf(dtv * Ac[0]);
                an[0] = a0;
                #pragma unroll
                for (int n = 1; n < 16; ++n) an[n] = an[n-1] * a0;
            } else {
                #pragma unroll
                for (int n = 0; n < 16; ++n) an[n] = __expf(dtv * Ac[n]);
            }
            #pragma unroll
            for (int n = 0; n < 16; ++n) {
                s[n] = fmaf(an[n], s[n], xd_s[t*68 + 16 + n] * dx);
                p[n] *= an[n];
            }
        }
        size_t base = ((size_t)(b*NCH + c) * DI + d) * 16;
        u16x8 pv0, pv1, sv0, sv1;
        #pragma unroll
        for (int n = 0; n < 8; ++n) {
            pv0[n] = f2bfu(p[n]);   pv1[n] = f2bfu(p[8+n]);
            sv0[n] = f2bfu(s[n]);   sv1[n] = f2bfu(s[8+n]);
        }
        *(u16x8*)(Pb + base)     = pv0;  *(u16x8*)(Pb + base + 8) = pv1;
        *(u16x8*)(Sb + base)     = sv0;  *(u16x8*)(Sb + base + 8) = sv1;
    }
}

/* ---------------- scanB: stitch chunk entry states (bf16 P,S -> f32 H) -------- */
__global__ __launch_bounds__(256) void scanB_k(
    const u16* __restrict__ Pb, const u16* __restrict__ Sb,
    float* __restrict__ H) {
    int i = blockIdx.x * 256 + threadIdx.x;   /* BATCH*DI*DS/4 = 4096 */
    int b = i >> 11, j4 = i & 2047;
    f32x4 h = {0.f, 0.f, 0.f, 0.f};
    for (int c = 0; c < NCH; ++c) {
        size_t i4 = (size_t)(b*NCH + c) * 2048 + j4;
        u16x4 pv = ((const u16x4*)Pb)[i4];
        u16x4 sv = ((const u16x4*)Sb)[i4];
        ((f32x4*)H)[i4] = h;
        #pragma unroll
        for (int j = 0; j < 4; ++j) h[j] = fmaf(bfu2f(pv[j]), h[j], bfu2f(sv[j]));
    }
}

/* ---------------- fused C: scan replay -> y slab (LDS) -> out_proj MFMA ------- */
/* grid (NCH, BATCH), 512 threads. Out: l0 -> bf16 z2, l1 -> f32 d_out. */
__global__ __launch_bounds__(512) void fused_c_k(
    const u16* __restrict__ xcb, const u16* __restrict__ dtob,
    const float* __restrict__ BCg, const float* __restrict__ H,
    const float* __restrict__ Alog, const float* __restrict__ Dp,
    const u16* __restrict__ xz, const __bf16* __restrict__ outw,
    u16* __restrict__ Ob, float* __restrict__ Of) {
    __shared__ u16 y_s[CLEN * XCP];        /* 33.3 KB */
    __shared__ float BCs[CLEN * 32];       /* 4 KB */
    int tid = threadIdx.x;
    int c = blockIdx.x, b = blockIdx.y;
    int bl0 = b * LSEQ + c * CLEN;
    int d = tid;

    for (int i = tid; i < CLEN * 32; i += 512)
        BCs[i] = BCg[(size_t)(b*NCH + c) * (CLEN*32) + i];

    float Ac[16], h[16];
    {
        const f32x4* a4 = (const f32x4*)(Alog + (size_t)d * 16);
        const f32x4* h4 = (const f32x4*)(H + ((size_t)(b*NCH + c) * DI + d) * 16);
        #pragma unroll
        for (int g = 0; g < 4; ++g) {
            f32x4 av = a4[g]; f32x4 hv = h4[g];
            #pragma unroll
            for (int j = 0; j < 4; ++j) { Ac[g*4+j] = -__expf(av[j]); h[g*4+j] = hv[j]; }
        }
    }
    bool fastp = true;
    #pragma unroll
    for (int n = 1; n < 16; ++n)
        fastp = fastp && (fabsf(Ac[n] - (float)(n+1) * Ac[0]) <= 1e-4f * fabsf(Ac[n]));
    float Dv = Dp[d];
    __syncthreads();

    #pragma unroll 4
    for (int t = 0; t < CLEN; ++t) {
        float dtv = bfu2f(dtob[(size_t)(bl0 + t) * DI + d]);
        float xv  = bfu2f(xcb[(size_t)(bl0 + t) * DI + d]);
        float gv  = bfu2f(xz[(size_t)(bl0 + t) * 1024 + DI + d]);
        float dx = dtv * xv;
        float an[16];
        if (fastp) {
            float a0 = __expf(dtv * Ac[0]);
            an[0] = a0;
            #pragma unroll
            for (int n = 1; n < 16; ++n) an[n] = an[n-1] * a0;
        } else {
            #pragma unroll
            for (int n = 0; n < 16; ++n) an[n] = __expf(dtv * Ac[n]);
        }
        float y = 0.f;
        #pragma unroll
        for (int n = 0; n < 16; ++n) {
            h[n] = fmaf(an[n], h[n], BCs[t*32 + n] * dx);
            y = fmaf(h[n], BCs[t*32 + 16 + n], y);
        }
        float yv = fmaf(xv, Dv, y) * siluf(gv);
        y_s[t * XCP + d] = f2bfu(yv);
    }
    __syncthreads();

    /* out_proj: O[32,256] = y_s[32,512] @ outw[256,512]^T; 8 waves: mt 2 x ng 4 */
    {
        int wave = tid >> 6, lane = tid & 63;
        int row = lane & 15, q = lane >> 4;
        int mt = wave & 1, ng = wave >> 1;         /* ng: 64-col group */
        f32x4 acc[4] = {};
        #pragma unroll
        for (int kb = 0; kb < 16; ++kb) {
            bf16x8 a = *(const bf16x8*)&y_s[(mt*16 + row) * XCP + kb*32 + q*8];
            #pragma unroll
            for (int ni = 0; ni < 4; ++ni) {
                bf16x8 bb = *(const bf16x8*)(outw +
                    (size_t)(ng*64 + ni*16 + row) * 512 + kb*32 + q*8);
                acc[ni] = __builtin_amdgcn_mfma_f32_16x16x32_bf16(a, bb, acc[ni], 0, 0, 0);
            }
        }
        #pragma unroll
        for (int r = 0; r < 4; ++r) {
            size_t gr = (size_t)(bl0 + mt*16 + q*4 + r) * DM;
            #pragma unroll
            for (int ni = 0; ni < 4; ++ni) {
                int gc = ng*64 + ni*16 + row;
                if (Ob) Ob[gr + gc] = f2bfu(acc[ni][r]);
                else    Of[gr + gc] = acc[ni][r];
            }
        }
    }
}

/* ================================================================== */
extern "C" void kernel_launch(void* const* d_in, const int* in_sizes, int n_in,
                              void* d_out, int out_size, void* d_ws, size_t ws_size,
                              hipStream_t stream) {
    (void)in_sizes; (void)n_in; (void)out_size; (void)ws_size;
    const float* z_in   = (const float*)d_in[0];
    const float* in_w   = (const float*)d_in[1];
    const float* conv_w = (const float*)d_in[2];
    const float* conv_b = (const float*)d_in[3];
    const float* xp_w   = (const float*)d_in[4];
    const float* dt_w   = (const float*)d_in[5];
    const float* dt_b   = (const float*)d_in[6];
    const float* A_log  = (const float*)d_in[7];
    const float* D_par  = (const float*)d_in[8];
    const float* out_w  = (const float*)d_in[9];
    float* outp = (float*)d_out;

    char* p = (char*)d_ws;
    auto alloc = [&](size_t bytes) { char* r = p; p += (bytes + 255) & ~(size_t)255; return r; };
    u16* z_bf    = (u16*)alloc((size_t)BLROWS*DM*2);
    u16* z2_bf   = (u16*)alloc((size_t)BLROWS*DM*2);
    u16* xz_bf   = (u16*)alloc((size_t)BLROWS*1024*2);
    u16* xc_bf   = (u16*)alloc((size_t)BLROWS*DI*2);
    u16* dt_bf   = (u16*)alloc((size_t)BLROWS*DI*2);
    u16* inw_bf  = (u16*)alloc((size_t)2*1024*256*2);
    u16* outw_bf = (u16*)alloc((size_t)2*256*512*2);
    u16* xpw_bf  = (u16*)alloc((size_t)2*64*512*2);
    float* BCg   = (float*)alloc((size_t)BATCH*NCH*CLEN*32*4);
    u16* Pbuf    = (u16*)alloc((size_t)BATCH*NCH*DI*DS*2);
    u16* Sbuf    = (u16*)alloc((size_t)BATCH*NCH*DI*DS*2);
    float* Hbuf  = (float*)alloc((size_t)BATCH*NCH*DI*DS*4);

    cast_all_k<<<(N_INW + N_OUTW + N_XPW + N_Z)/256, 256, 0, stream>>>(
        in_w, out_w, xp_w, z_in, inw_bf, outw_bf, xpw_bf, z_bf);

    const u16* zcur = z_bf;
    for (int l = 0; l < 2; ++l) {
        gemm_in_k<<<dim3(BLROWS/128, 1024/128), 256, 0, stream>>>(
            (const __bf16*)zcur, (const __bf16*)(inw_bf + (size_t)l*1024*256),
            xz_bf, BLROWS, 1024, 256);
        fused_a_k<<<dim3(NCH, BATCH), 512, 0, stream>>>(
            xz_bf, conv_w + (size_t)l*DI*4, conv_b + (size_t)l*DI,
            (const __bf16*)(xpw_bf + (size_t)l*64*512),
            dt_w + (size_t)l*DI*16, dt_b + (size_t)l*DI,
            A_log + (size_t)l*DI*DS,
            xc_bf, dt_bf, BCg, Pbuf, Sbuf);
        scanB_k<<<16, 256, 0, stream>>>(Pbuf, Sbuf, Hbuf);
        fused_c_k<<<dim3(NCH, BATCH), 512, 0, stream>>>(
            xc_bf, dt_bf, BCg, Hbuf,
            A_log + (size_t)l*DI*DS, D_par + (size_t)l*DI,
            xz_bf, (const __bf16*)(outw_bf + (size_t)l*256*512),
            (l == 0) ? z2_bf : nullptr, (l == 1) ? outp : nullptr);
        zcur = z2_bf;
    }
}